// Round 3
// baseline (795.779 us; speedup 1.0000x reference)
//
#include <hip/hip_runtime.h>

#define DD 32   // node/output dim
#define HH 64   // psi hidden
// PSI_IN = 5*32 = 160

#define XSTR 72   // bf16 stride for xbuf rows (16B-aligned b128 reads)
#define DSTR 33   // f32 stride for hdiff rows (<=3-way bank conflicts)

typedef __attribute__((ext_vector_type(8))) short bf16x8;   // 8 bf16 = 4 VGPRs
typedef __attribute__((ext_vector_type(4))) float f32x4;

static __device__ __forceinline__ unsigned short f2bf(float x) {
    // round-to-nearest-even bf16 (inputs are finite; no NaN handling needed)
    union { float f; unsigned u; } v; v.f = x;
    unsigned r = (v.u + 0x7FFFu + ((v.u >> 16) & 1u)) >> 16;
    return (unsigned short)r;
}

static __device__ __forceinline__ float bf2f(unsigned short x) {
    union { unsigned u; float f; } v; v.u = ((unsigned)x) << 16;
    return v.f;
}

// Convert w0/w1/w2 to bf16 MFMA B-fragment order.
// 32 frags total: [0..19] = w0 (kk*4+t), [20..27] = w1 (kk*4+t), [28..31] = w2 (kk*2+t).
__global__ __launch_bounds__(256) void prep_weights(
    const float* __restrict__ w0, const float* __restrict__ w1,
    const float* __restrict__ w2, unsigned short* __restrict__ frags)
{
    const int tid = blockIdx.x * 256 + threadIdx.x;
    const int f = tid >> 6, l = tid & 63;
    if (f >= 32) return;
    const int c = l & 15, q = l >> 4;
    unsigned short* dst = frags + f * 512 + l * 8;
    if (f < 20) {
        const int kk = f >> 2, t = f & 3;
        const int n = t * 16 + c, kb = kk * 32 + q * 8;
        #pragma unroll
        for (int j = 0; j < 8; ++j) dst[j] = f2bf(w0[(kb + j) * HH + n]);
    } else if (f < 28) {
        const int f2 = f - 20, kk = f2 >> 2, t = f2 & 3;
        const int n = t * 16 + c, kb = kk * 32 + q * 8;
        #pragma unroll
        for (int j = 0; j < 8; ++j) dst[j] = f2bf(w1[(kb + j) * HH + n]);
    } else {
        const int f3 = f - 28, kk = f3 >> 1, t = f3 & 1;
        const int n = t * 16 + c, kb = kk * 32 + q * 8;
        #pragma unroll
        for (int j = 0; j < 8; ++j) dst[j] = f2bf(w2[(kb + j) * DD + n]);
    }
}

// Pack per-node features into ONE 128B bf16 row: npack[n] = [h_s[n][0..31] | h_d[n][0..31]].
__global__ __launch_bounds__(256) void pack_nodes(
    const float* __restrict__ h_d, const float* __restrict__ h_s,
    unsigned short* __restrict__ npack, int N)
{
    const int tid = blockIdx.x * 256 + threadIdx.x;   // one thread per 8 elems
    if (tid >= N * 8) return;
    const int n = tid >> 3, chunk = tid & 7;
    const float* src = (chunk < 4) ? (h_s + (size_t)n * DD + chunk * 8)
                                   : (h_d + (size_t)n * DD + (chunk - 4) * 8);
    const float4 v0 = ((const float4*)src)[0];
    const float4 v1 = ((const float4*)src)[1];
    unsigned short* dst = npack + (size_t)n * 64 + chunk * 8;
    dst[0] = f2bf(v0.x); dst[1] = f2bf(v0.y); dst[2] = f2bf(v0.z); dst[3] = f2bf(v0.w);
    dst[4] = f2bf(v1.x); dst[5] = f2bf(v1.y); dst[6] = f2bf(v1.z); dst[7] = f2bf(v1.w);
}

// ---- counting sort of edges by receiver: hist -> scan -> scatter ----
__global__ __launch_bounds__(256) void hist_kernel(
    const int* __restrict__ rcv, int* __restrict__ cnt, int E)
{
    const int i = blockIdx.x * 256 + threadIdx.x;
    if (i < E) atomicAdd(cnt + rcv[i], 1);
}

// single-block exclusive scan over cnt[0..n): thread-serial chunks + block scan
__global__ __launch_bounds__(1024) void scan_kernel(int* __restrict__ cnt, int n)
{
    __shared__ int sums[1024];
    const int t = threadIdx.x;
    const int chunk = (n + 1023) >> 10;
    const int lo = t * chunk;
    const int hi = (lo + chunk < n) ? lo + chunk : n;
    int s = 0;
    for (int i = lo; i < hi; ++i) s += cnt[i];
    sums[t] = s;
    __syncthreads();
    for (int d = 1; d < 1024; d <<= 1) {          // Hillis-Steele inclusive
        int v = (t >= d) ? sums[t - d] : 0;
        __syncthreads();
        sums[t] += v;
        __syncthreads();
    }
    int run = (t > 0) ? sums[t - 1] : 0;          // exclusive offset for this chunk
    for (int i = lo; i < hi; ++i) { const int old = cnt[i]; cnt[i] = run; run += old; }
}

// scatter into receiver-sorted order; also materialize sorted snd/rcv so the hot
// kernel reads indices fully coalesced (no 4B gather amplification).
__global__ __launch_bounds__(256) void scatter_kernel(
    const int* __restrict__ snd, const int* __restrict__ rcv, int* __restrict__ cnt,
    int* __restrict__ perm, int* __restrict__ snd_s, int* __restrict__ rcv_s, int E)
{
    const int i = blockIdx.x * 256 + threadIdx.x;
    if (i >= E) return;
    const int r = rcv[i];
    const int pos = atomicAdd(cnt + r, 1);
    perm[pos] = i;
    snd_s[pos] = snd[i];
    rcv_s[pos] = r;
}

// One wave per 16-edge tile, waves take CONTIGUOUS tile chunks (receiver runs stay
// on one XCD's L2). Edges are receiver-sorted: receiver gathers + epilogue atomics
// hit ~8-edge runs of the same node row -> L2-resident. Sender gathers stay random
// (~100 MB compulsory). ef gathered through perm (full-line, non-temporal).
__global__ __launch_bounds__(512, 4) void edge_mfma(
    const unsigned short* __restrict__ npack,
    const float* __restrict__ ef,
    const int* __restrict__ perm,
    const int* __restrict__ snd_s, const int* __restrict__ rcv_s,
    const unsigned short* __restrict__ frags,
    const float* __restrict__ b0, const float* __restrict__ b1,
    const float* __restrict__ b2,
    float* __restrict__ agg, int E, int ntiles)
{
    __shared__ __align__(16) unsigned short wlds[20 * 512];      // 20 KB: w0 frags
    __shared__ __align__(16) unsigned short xbuf[8][16 * XSTR];  // 18 KB: x1/x2 (reused)
    __shared__ float hdiff[8][16 * DSTR];                        // 16.9 KB -> 55.8 KB total

    const int lane = threadIdx.x & 63;
    const int w = threadIdx.x >> 6;          // wave in block, 0..7
    const int c = lane & 15, q = lane >> 4;

    // stage w0 fragments to LDS (20 KB, coalesced)
    for (int i = threadIdx.x; i < 20 * 512 / 8; i += 512)
        ((float4*)wlds)[i] = ((const float4*)frags)[i];
    // w1 (8 frags) + w2 (4 frags) in registers
    bf16x8 wf1[8], wf2[4];
    #pragma unroll
    for (int t = 0; t < 8; ++t)
        wf1[t] = *(const bf16x8*)(frags + (20 + t) * 512 + lane * 8);
    #pragma unroll
    for (int t = 0; t < 4; ++t)
        wf2[t] = *(const bf16x8*)(frags + (28 + t) * 512 + lane * 8);
    __syncthreads();

    const float b0t[4] = {b0[c], b0[16 + c], b0[32 + c], b0[48 + c]};
    const float b1t[4] = {b1[c], b1[16 + c], b1[32 + c], b1[48 + c]};
    const float b2t[2] = {b2[c], b2[16 + c]};

    unsigned short* xb = xbuf[w];
    float* hd = hdiff[w];

    const int wave_id = blockIdx.x * 8 + w;
    const int nwaves = gridDim.x * 8;
    const int per = (ntiles + nwaves - 1) / nwaves;
    const int tile0 = wave_id * per;
    const int tile1 = (tile0 + per < ntiles) ? tile0 + per : ntiles;

    for (int tile = tile0; tile < tile1; ++tile) {
        const int base = tile * 16;
        int p = base + c; if (p >= E) p = E - 1;   // sorted position; m-row = c
        const int si = snd_s[p];                   // coalesced
        const int ri = rcv_s[p];                   // coalesced, ~8-runs equal
        const int ee = perm[p];                    // original edge id for ef row

        // ---- gather: 2 packed node rows + ef row via perm ----
        const unsigned short* nps = npack + (size_t)si * 64 + q * 8;
        const unsigned short* npr = npack + (size_t)ri * 64 + q * 8;
        const bf16x8 a_ss = *(const bf16x8*)nps;          // h_s[sender]
        const bf16x8 a_sr = *(const bf16x8*)npr;          // h_s[receiver]
        const bf16x8 a_ds = *(const bf16x8*)(nps + 32);   // h_d[sender]
        const bf16x8 a_dr = *(const bf16x8*)(npr + 32);   // h_d[receiver]
        const f32x4 e0v = __builtin_nontemporal_load((const f32x4*)(ef + (size_t)ee * DD + q * 8));
        const f32x4 e1v = __builtin_nontemporal_load((const f32x4*)(ef + (size_t)ee * DD + q * 8) + 1);

        // stash h_dj - h_di (row c, cols q*8..) for the transposed epilogue
        #pragma unroll
        for (int j = 0; j < 8; ++j)
            hd[c * DSTR + q * 8 + j] =
                bf2f((unsigned short)a_dr[j]) - bf2f((unsigned short)a_ds[j]);

        bf16x8 aef;
        aef[0] = (short)f2bf(e0v[0]); aef[1] = (short)f2bf(e0v[1]);
        aef[2] = (short)f2bf(e0v[2]); aef[3] = (short)f2bf(e0v[3]);
        aef[4] = (short)f2bf(e1v[0]); aef[5] = (short)f2bf(e1v[1]);
        aef[6] = (short)f2bf(e1v[2]); aef[7] = (short)f2bf(e1v[3]);

        // ---- layer 0: [16x160] @ [160x64] ----
        const bf16x8 af[5] = {a_ss, a_sr, a_ds, a_dr, aef};
        f32x4 c0[4] = {f32x4{0,0,0,0}, f32x4{0,0,0,0}, f32x4{0,0,0,0}, f32x4{0,0,0,0}};
        #pragma unroll
        for (int kk = 0; kk < 5; ++kk) {
            #pragma unroll
            for (int t = 0; t < 4; ++t) {
                const bf16x8 b = *(const bf16x8*)(wlds + (kk * 4 + t) * 512 + lane * 8);
                c0[t] = __builtin_amdgcn_mfma_f32_16x16x32_bf16(af[kk], b, c0[t], 0, 0, 0);
            }
        }
        #pragma unroll
        for (int t = 0; t < 4; ++t) {
            #pragma unroll
            for (int r = 0; r < 4; ++r) {
                const float v = fmaxf(c0[t][r] + b0t[t], 0.0f);
                xb[(q * 4 + r) * XSTR + t * 16 + c] = f2bf(v);
            }
        }

        // ---- layer 1: [16x64] @ [64x64], B from registers ----
        f32x4 c1[4] = {f32x4{0,0,0,0}, f32x4{0,0,0,0}, f32x4{0,0,0,0}, f32x4{0,0,0,0}};
        #pragma unroll
        for (int kk = 0; kk < 2; ++kk) {
            const bf16x8 a = *(const bf16x8*)(xb + c * XSTR + kk * 32 + q * 8);
            #pragma unroll
            for (int t = 0; t < 4; ++t)
                c1[t] = __builtin_amdgcn_mfma_f32_16x16x32_bf16(a, wf1[kk * 4 + t], c1[t], 0, 0, 0);
        }
        #pragma unroll
        for (int t = 0; t < 4; ++t) {
            #pragma unroll
            for (int r = 0; r < 4; ++r) {
                const float v = fmaxf(c1[t][r] + b1t[t], 0.0f);
                xb[(q * 4 + r) * XSTR + t * 16 + c] = f2bf(v);
            }
        }

        // ---- layer 2: [16x64] @ [64x32], B from registers ----
        f32x4 c2[2] = {f32x4{0,0,0,0}, f32x4{0,0,0,0}};
        #pragma unroll
        for (int kk = 0; kk < 2; ++kk) {
            const bf16x8 a = *(const bf16x8*)(xb + c * XSTR + kk * 32 + q * 8);
            #pragma unroll
            for (int t = 0; t < 2; ++t)
                c2[t] = __builtin_amdgcn_mfma_f32_16x16x32_bf16(a, wf2[kk * 2 + t], c2[t], 0, 0, 0);
        }

        // ---- epilogue: s_ij = relu(psi)*(h_dj - h_di), scatter-add (L2-hot rows) ----
        const int4 rr4 = *(const int4*)(rcv_s + base + q * 4);   // padded array
        const int rir[4] = {rr4.x, rr4.y, rr4.z, rr4.w};
        #pragma unroll
        for (int t = 0; t < 2; ++t) {
            const int h = t * 16 + c;               // C/D col = output dim
            #pragma unroll
            for (int r = 0; r < 4; ++r) {
                const int pp = base + q * 4 + r;    // C/D row = sorted position
                if (pp < E) {
                    const float psi = fmaxf(c2[t][r] + b2t[t], 0.0f);
                    const float d = hd[(q * 4 + r) * DSTR + h];
                    atomicAdd(agg + (size_t)rir[r] * DD + h, psi * d);
                }
            }
        }
    }
}

// out[n][d] = h_d_prev[n][d] + sum_k agg[n][k] * W[k][d]
__global__ __launch_bounds__(256) void out_kernel(
    const float* __restrict__ h_d, const float* __restrict__ agg,
    const float* __restrict__ W, float* __restrict__ out, int N)
{
    const int idx = blockIdx.x * 256 + threadIdx.x;
    if (idx >= N * DD) return;
    const int n = idx >> 5;
    const int d = idx & 31;
    const float* arow = agg + (size_t)n * DD;
    float s = h_d[idx];
    #pragma unroll
    for (int k = 0; k < DD; ++k) s = fmaf(arow[k], W[k * DD + d], s);
    out[idx] = s;
}

extern "C" void kernel_launch(void* const* d_in, const int* in_sizes, int n_in,
                              void* d_out, int out_size, void* d_ws, size_t ws_size,
                              hipStream_t stream) {
    const float* h_d = (const float*)d_in[0];
    const float* h_s = (const float*)d_in[1];
    const float* ef  = (const float*)d_in[2];
    const int*   snd = (const int*)d_in[3];
    const int*   rcv = (const int*)d_in[4];
    const float* w0  = (const float*)d_in[5];
    const float* b0  = (const float*)d_in[6];
    const float* w1  = (const float*)d_in[7];
    const float* b1  = (const float*)d_in[8];
    const float* w2  = (const float*)d_in[9];
    const float* b2  = (const float*)d_in[10];
    const float* W   = (const float*)d_in[11];
    float* out = (float*)d_out;

    const int N = in_sizes[0] / DD;
    const int E = in_sizes[3];
    const int ntiles = (E + 15) / 16;

    // workspace layout (256B-aligned chunks)
    char* ws = (char*)d_ws;
    size_t off = 0;
    auto walloc = [&](size_t bytes) {
        char* ptr = ws + off; off += (bytes + 255) & ~(size_t)255; return ptr;
    };
    float* agg            = (float*)walloc((size_t)N * DD * sizeof(float));
    unsigned short* frags = (unsigned short*)walloc(32 * 512 * sizeof(unsigned short));
    unsigned short* npack = (unsigned short*)walloc((size_t)N * 64 * sizeof(unsigned short));
    int* cnt              = (int*)walloc((size_t)(N + 1) * sizeof(int));
    int* perm             = (int*)walloc((size_t)E * sizeof(int));
    int* snd_s            = (int*)walloc((size_t)E * sizeof(int));
    int* rcv_s            = (int*)walloc((size_t)(E + 16) * sizeof(int));  // padded for int4 tail

    hipMemsetAsync(agg, 0, (size_t)N * DD * sizeof(float), stream);
    hipMemsetAsync(cnt, 0, (size_t)(N + 1) * sizeof(int), stream);
    prep_weights<<<8, 256, 0, stream>>>(w0, w1, w2, frags);
    pack_nodes<<<(N * 8 + 255) / 256, 256, 0, stream>>>(h_d, h_s, npack, N);
    hist_kernel<<<(E + 255) / 256, 256, 0, stream>>>(rcv, cnt, E);
    scan_kernel<<<1, 1024, 0, stream>>>(cnt, N);
    scatter_kernel<<<(E + 255) / 256, 256, 0, stream>>>(snd, rcv, cnt, perm, snd_s, rcv_s, E);
    edge_mfma<<<512, 512, 0, stream>>>(npack, ef, perm, snd_s, rcv_s, frags,
                                       b0, b1, b2, agg, E, ntiles);
    out_kernel<<<((N * DD) + 255) / 256, 256, 0, stream>>>(h_d, agg, W, out, N);
}

// Round 5
// 497.209 us; speedup vs baseline: 1.6005x; 1.6005x over previous
//
#include <hip/hip_runtime.h>

#define DD 32   // node/output dim
#define HH 64   // psi hidden
// PSI_IN = 5*32 = 160

#define XSTR 72   // bf16 stride for xbuf rows (16B-aligned b128 reads)
#define DSTR 33   // f32 stride for hdiff rows

typedef __attribute__((ext_vector_type(8))) short bf16x8;   // 8 bf16 = 4 VGPRs
typedef __attribute__((ext_vector_type(4))) float f32x4;

static __device__ __forceinline__ unsigned short f2bf(float x) {
    // round-to-nearest-even bf16 (inputs are finite; no NaN handling needed)
    union { float f; unsigned u; } v; v.f = x;
    unsigned r = (v.u + 0x7FFFu + ((v.u >> 16) & 1u)) >> 16;
    return (unsigned short)r;
}

static __device__ __forceinline__ float bf2f(unsigned short x) {
    union { unsigned u; float f; } v; v.u = ((unsigned)x) << 16;
    return v.f;
}

// Convert w0/w1/w2 to bf16 MFMA B-fragment order.
// 32 frags total: [0..19] = w0 (kk*4+t), [20..27] = w1 (kk*4+t), [28..31] = w2 (kk*2+t).
__global__ __launch_bounds__(256) void prep_weights(
    const float* __restrict__ w0, const float* __restrict__ w1,
    const float* __restrict__ w2, unsigned short* __restrict__ frags)
{
    const int tid = blockIdx.x * 256 + threadIdx.x;
    const int f = tid >> 6, l = tid & 63;
    if (f >= 32) return;
    const int c = l & 15, q = l >> 4;
    unsigned short* dst = frags + f * 512 + l * 8;
    if (f < 20) {
        const int kk = f >> 2, t = f & 3;
        const int n = t * 16 + c, kb = kk * 32 + q * 8;
        #pragma unroll
        for (int j = 0; j < 8; ++j) dst[j] = f2bf(w0[(kb + j) * HH + n]);
    } else if (f < 28) {
        const int f2 = f - 20, kk = f2 >> 2, t = f2 & 3;
        const int n = t * 16 + c, kb = kk * 32 + q * 8;
        #pragma unroll
        for (int j = 0; j < 8; ++j) dst[j] = f2bf(w1[(kb + j) * HH + n]);
    } else {
        const int f3 = f - 28, kk = f3 >> 1, t = f3 & 1;
        const int n = t * 16 + c, kb = kk * 32 + q * 8;
        #pragma unroll
        for (int j = 0; j < 8; ++j) dst[j] = f2bf(w2[(kb + j) * DD + n]);
    }
}

// Pack nodes into one 128B bf16 row [h_s | h_d]; fused receiver histogram (cnt may be null).
__global__ __launch_bounds__(256) void pack_hist(
    const float* __restrict__ h_d, const float* __restrict__ h_s,
    unsigned short* __restrict__ npack,
    const int* __restrict__ rcv, int* __restrict__ cnt, int N, int E)
{
    const int tid = blockIdx.x * 256 + threadIdx.x;
    if (tid < N * 8) {
        const int n = tid >> 3, chunk = tid & 7;
        const float* src = (chunk < 4) ? (h_s + (size_t)n * DD + chunk * 8)
                                       : (h_d + (size_t)n * DD + (chunk - 4) * 8);
        const float4 v0 = ((const float4*)src)[0];
        const float4 v1 = ((const float4*)src)[1];
        unsigned short* dst = npack + (size_t)n * 64 + chunk * 8;
        dst[0] = f2bf(v0.x); dst[1] = f2bf(v0.y); dst[2] = f2bf(v0.z); dst[3] = f2bf(v0.w);
        dst[4] = f2bf(v1.x); dst[5] = f2bf(v1.y); dst[6] = f2bf(v1.z); dst[7] = f2bf(v1.w);
    }
    if (cnt != nullptr && tid < E) atomicAdd(cnt + rcv[tid], 1);
}

// Distributed 2-level exclusive scan over cnt[0..N): scan1 (per-1024 block) + scan2 (block sums).
__global__ __launch_bounds__(1024) void scan1(int* __restrict__ cnt, int* __restrict__ btot, int N)
{
    __shared__ int s[1024];
    const int t = threadIdx.x;
    const int i = blockIdx.x * 1024 + t;
    const int v = (i < N) ? cnt[i] : 0;
    s[t] = v; __syncthreads();
    for (int d = 1; d < 1024; d <<= 1) {
        const int x = (t >= d) ? s[t - d] : 0;
        __syncthreads(); s[t] += x; __syncthreads();
    }
    if (i < N) cnt[i] = s[t] - v;                 // local exclusive prefix
    if (t == 1023) btot[blockIdx.x] = s[1023];    // block total
}

__global__ __launch_bounds__(128) void scan2(
    const int* __restrict__ btot, int* __restrict__ boffs, int nb)
{
    __shared__ int s[128];
    const int t = threadIdx.x;
    const int v = (t < nb) ? btot[t] : 0;
    s[t] = v; __syncthreads();
    for (int d = 1; d < 128; d <<= 1) {
        const int x = (t >= d) ? s[t - d] : 0;
        __syncthreads(); s[t] += x; __syncthreads();
    }
    if (t < nb) boffs[t] = s[t] - v;              // exclusive block offsets
}

// Write only perm (4B/edge). Post-condition: cnt[r] = local_excl[r] + deg[r], so
// global end(n) = cnt[n] + boffs[n>>10] and start(n) = end(n-1).
__global__ __launch_bounds__(256) void scatter_perm(
    const int* __restrict__ rcv, int* __restrict__ cnt, const int* __restrict__ boffs,
    int* __restrict__ perm, int E)
{
    const int i = blockIdx.x * 256 + threadIdx.x;
    if (i >= E) return;
    const int r = rcv[i];
    const int pos = atomicAdd(cnt + r, 1) + boffs[r >> 10];
    perm[pos] = i;
}

// PASS A: per-edge psi MLP + s_ij = relu(psi)*(h_dj - h_di), written as bf16 rows in
// ORIGINAL edge order (every stream coalesced; ef stays a clean stream; NO atomics).
__global__ __launch_bounds__(512, 4) void edge_psi(
    const unsigned short* __restrict__ npack,
    const float* __restrict__ ef,
    const int* __restrict__ snd, const int* __restrict__ rcv,
    const unsigned short* __restrict__ frags,
    const float* __restrict__ b0, const float* __restrict__ b1,
    const float* __restrict__ b2,
    unsigned short* __restrict__ sij, int E, int ntiles)
{
    __shared__ __align__(16) unsigned short wlds[20 * 512];      // 20 KB: w0 frags
    __shared__ __align__(16) unsigned short xbuf[8][16 * XSTR];  // 18 KB: x1/x2/sij staging
    __shared__ float hdiff[8][16 * DSTR];                        // 16.5 KB -> 55.8 KB total

    const int lane = threadIdx.x & 63;
    const int w = threadIdx.x >> 6;
    const int c = lane & 15, q = lane >> 4;

    for (int i = threadIdx.x; i < 20 * 512 / 8; i += 512)
        ((float4*)wlds)[i] = ((const float4*)frags)[i];
    bf16x8 wf1[8], wf2[4];
    #pragma unroll
    for (int t = 0; t < 8; ++t)
        wf1[t] = *(const bf16x8*)(frags + (20 + t) * 512 + lane * 8);
    #pragma unroll
    for (int t = 0; t < 4; ++t)
        wf2[t] = *(const bf16x8*)(frags + (28 + t) * 512 + lane * 8);
    __syncthreads();

    const float b0t[4] = {b0[c], b0[16 + c], b0[32 + c], b0[48 + c]};
    const float b1t[4] = {b1[c], b1[16 + c], b1[32 + c], b1[48 + c]};
    const float b2t[2] = {b2[c], b2[16 + c]};

    unsigned short* xb = xbuf[w];
    float* hd = hdiff[w];

    const int wave_id = blockIdx.x * 8 + w;
    const int nwaves = gridDim.x * 8;

    int nsi = 0, nri = 0;
    if (wave_id < ntiles) {
        int e0 = wave_id * 16 + c; if (e0 >= E) e0 = E - 1;
        nsi = __builtin_nontemporal_load(snd + e0);
        nri = __builtin_nontemporal_load(rcv + e0);
    }

    for (int tile = wave_id; tile < ntiles; tile += nwaves) {
        const int base = tile * 16;
        const int si = nsi, ri = nri;
        {
            const int nt = tile + nwaves;
            if (nt < ntiles) {
                int e2 = nt * 16 + c; if (e2 >= E) e2 = E - 1;
                nsi = __builtin_nontemporal_load(snd + e2);
                nri = __builtin_nontemporal_load(rcv + e2);
            }
        }
        int e = base + c; if (e >= E) e = E - 1;

        // ---- gather: 2 packed node rows + streaming ef ----
        const unsigned short* nps = npack + (size_t)si * 64 + q * 8;
        const unsigned short* npr = npack + (size_t)ri * 64 + q * 8;
        const bf16x8 a_ss = *(const bf16x8*)nps;
        const bf16x8 a_sr = *(const bf16x8*)npr;
        const bf16x8 a_ds = *(const bf16x8*)(nps + 32);
        const bf16x8 a_dr = *(const bf16x8*)(npr + 32);
        const f32x4 e0v = __builtin_nontemporal_load((const f32x4*)(ef + (size_t)e * DD + q * 8));
        const f32x4 e1v = __builtin_nontemporal_load((const f32x4*)(ef + (size_t)e * DD + q * 8) + 1);

        #pragma unroll
        for (int j = 0; j < 8; ++j)
            hd[c * DSTR + q * 8 + j] =
                bf2f((unsigned short)a_dr[j]) - bf2f((unsigned short)a_ds[j]);

        bf16x8 aef;
        aef[0] = (short)f2bf(e0v[0]); aef[1] = (short)f2bf(e0v[1]);
        aef[2] = (short)f2bf(e0v[2]); aef[3] = (short)f2bf(e0v[3]);
        aef[4] = (short)f2bf(e1v[0]); aef[5] = (short)f2bf(e1v[1]);
        aef[6] = (short)f2bf(e1v[2]); aef[7] = (short)f2bf(e1v[3]);

        // ---- layer 0: [16x160] @ [160x64] ----
        const bf16x8 af[5] = {a_ss, a_sr, a_ds, a_dr, aef};
        f32x4 c0[4] = {f32x4{0,0,0,0}, f32x4{0,0,0,0}, f32x4{0,0,0,0}, f32x4{0,0,0,0}};
        #pragma unroll
        for (int kk = 0; kk < 5; ++kk) {
            #pragma unroll
            for (int t = 0; t < 4; ++t) {
                const bf16x8 b = *(const bf16x8*)(wlds + (kk * 4 + t) * 512 + lane * 8);
                c0[t] = __builtin_amdgcn_mfma_f32_16x16x32_bf16(af[kk], b, c0[t], 0, 0, 0);
            }
        }
        #pragma unroll
        for (int t = 0; t < 4; ++t) {
            #pragma unroll
            for (int r = 0; r < 4; ++r) {
                const float v = fmaxf(c0[t][r] + b0t[t], 0.0f);
                xb[(q * 4 + r) * XSTR + t * 16 + c] = f2bf(v);
            }
        }

        // ---- layer 1: [16x64] @ [64x64] ----
        f32x4 c1[4] = {f32x4{0,0,0,0}, f32x4{0,0,0,0}, f32x4{0,0,0,0}, f32x4{0,0,0,0}};
        #pragma unroll
        for (int kk = 0; kk < 2; ++kk) {
            const bf16x8 a = *(const bf16x8*)(xb + c * XSTR + kk * 32 + q * 8);
            #pragma unroll
            for (int t = 0; t < 4; ++t)
                c1[t] = __builtin_amdgcn_mfma_f32_16x16x32_bf16(a, wf1[kk * 4 + t], c1[t], 0, 0, 0);
        }
        #pragma unroll
        for (int t = 0; t < 4; ++t) {
            #pragma unroll
            for (int r = 0; r < 4; ++r) {
                const float v = fmaxf(c1[t][r] + b1t[t], 0.0f);
                xb[(q * 4 + r) * XSTR + t * 16 + c] = f2bf(v);
            }
        }

        // ---- layer 2: [16x64] @ [64x32] ----
        f32x4 c2[2] = {f32x4{0,0,0,0}, f32x4{0,0,0,0}};
        #pragma unroll
        for (int kk = 0; kk < 2; ++kk) {
            const bf16x8 a = *(const bf16x8*)(xb + c * XSTR + kk * 32 + q * 8);
            #pragma unroll
            for (int t = 0; t < 2; ++t)
                c2[t] = __builtin_amdgcn_mfma_f32_16x16x32_bf16(a, wf2[kk * 2 + t], c2[t], 0, 0, 0);
        }

        // ---- epilogue: s_ij -> LDS (bf16) -> coalesced NT stream (1 KB/tile) ----
        #pragma unroll
        for (int t = 0; t < 2; ++t) {
            #pragma unroll
            for (int r = 0; r < 4; ++r) {
                const float psi = fmaxf(c2[t][r] + b2t[t], 0.0f);
                const float v = psi * hd[(q * 4 + r) * DSTR + t * 16 + c];
                xb[(q * 4 + r) * XSTR + t * 16 + c] = f2bf(v);
            }
        }
        const int eo = base + c;                  // lane row = c, halves by q
        if (eo < E && q < 4) {
            const f32x4 vv = *(const f32x4*)(xb + c * XSTR + q * 8);
            __builtin_nontemporal_store(vv, (f32x4*)(sij + (size_t)eo * DD + q * 8));
        }
    }
}

// PASS B: conflict-free segmented sum over receiver-sorted CSR + fused @W + residual.
// 16 lanes per node (each lane owns 2 output cols); 4 nodes/wave, 16 nodes/block.
__global__ __launch_bounds__(256) void aggregate_out(
    const unsigned short* __restrict__ sij,
    const int* __restrict__ perm,
    const int* __restrict__ cnt, const int* __restrict__ boffs,
    const float* __restrict__ h_d, const float* __restrict__ W,
    float* __restrict__ out, int N)
{
    __shared__ float Wl[32 * 32];
    __shared__ float accT[4][4][33];
    const int t = threadIdx.x;
    for (int i = t; i < 1024; i += 256) Wl[i] = W[i];
    __syncthreads();

    const int w = t >> 6, lane = t & 63;
    const int ni = lane >> 4, d = lane & 15;       // node-in-wave, col-pair
    const int n = blockIdx.x * 16 + w * 4 + ni;
    if (n >= N) return;

    const int start = (n == 0) ? 0 : (cnt[n - 1] + boffs[(n - 1) >> 10]);
    const int end = cnt[n] + boffs[n >> 10];

    float ax = 0.0f, ay = 0.0f;
    for (int j = start; j < end; ++j) {
        const int p = perm[j];                                     // broadcast across 16 lanes
        const unsigned pv = *(const unsigned*)(sij + (size_t)p * DD + 2 * d);  // 64B/edge coalesced
        ax += bf2f((unsigned short)(pv & 0xffffu));
        ay += bf2f((unsigned short)(pv >> 16));
    }
    float* at = &accT[w][ni][0];
    at[2 * d] = ax; at[2 * d + 1] = ay;            // wave-local, DS in-order: no barrier

    const float2 hv = *(const float2*)(h_d + (size_t)n * DD + 2 * d);
    float ox = hv.x, oy = hv.y;
    #pragma unroll
    for (int k = 0; k < 32; ++k) {
        const float a = at[k];
        ox += a * Wl[k * 32 + 2 * d];
        oy += a * Wl[k * 32 + 2 * d + 1];
    }
    float2 ov; ov.x = ox; ov.y = oy;
    *(float2*)(out + (size_t)n * DD + 2 * d) = ov;
}

// ---------------- fallback path (proven R2): atomic aggregation ----------------
__global__ __launch_bounds__(512, 4) void edge_atomic(
    const unsigned short* __restrict__ npack,
    const float* __restrict__ ef,
    const int* __restrict__ snd, const int* __restrict__ rcv,
    const unsigned short* __restrict__ frags,
    const float* __restrict__ b0, const float* __restrict__ b1,
    const float* __restrict__ b2,
    float* __restrict__ agg, int E, int ntiles)
{
    __shared__ __align__(16) unsigned short wlds[20 * 512];
    __shared__ __align__(16) unsigned short xbuf[8][16 * XSTR];
    __shared__ float hdiff[8][16 * DSTR];
    __shared__ int rcvb[8][16];

    const int lane = threadIdx.x & 63;
    const int w = threadIdx.x >> 6;
    const int c = lane & 15, q = lane >> 4;

    for (int i = threadIdx.x; i < 20 * 512 / 8; i += 512)
        ((float4*)wlds)[i] = ((const float4*)frags)[i];
    bf16x8 wf1[8], wf2[4];
    #pragma unroll
    for (int t = 0; t < 8; ++t)
        wf1[t] = *(const bf16x8*)(frags + (20 + t) * 512 + lane * 8);
    #pragma unroll
    for (int t = 0; t < 4; ++t)
        wf2[t] = *(const bf16x8*)(frags + (28 + t) * 512 + lane * 8);
    __syncthreads();

    const float b0t[4] = {b0[c], b0[16 + c], b0[32 + c], b0[48 + c]};
    const float b1t[4] = {b1[c], b1[16 + c], b1[32 + c], b1[48 + c]};
    const float b2t[2] = {b2[c], b2[16 + c]};

    unsigned short* xb = xbuf[w];
    float* hd = hdiff[w];
    int* rb = rcvb[w];

    const int wave_id = blockIdx.x * 8 + w;
    const int nwaves = gridDim.x * 8;

    int nsi = 0, nri = 0;
    if (wave_id < ntiles) {
        int e0 = wave_id * 16 + c; if (e0 >= E) e0 = E - 1;
        nsi = __builtin_nontemporal_load(snd + e0);
        nri = __builtin_nontemporal_load(rcv + e0);
    }

    for (int tile = wave_id; tile < ntiles; tile += nwaves) {
        const int base = tile * 16;
        const int si = nsi, ri = nri;
        {
            const int nt = tile + nwaves;
            if (nt < ntiles) {
                int e2 = nt * 16 + c; if (e2 >= E) e2 = E - 1;
                nsi = __builtin_nontemporal_load(snd + e2);
                nri = __builtin_nontemporal_load(rcv + e2);
            }
        }
        int e = base + c; if (e >= E) e = E - 1;

        const unsigned short* nps = npack + (size_t)si * 64 + q * 8;
        const unsigned short* npr = npack + (size_t)ri * 64 + q * 8;
        const bf16x8 a_ss = *(const bf16x8*)nps;
        const bf16x8 a_sr = *(const bf16x8*)npr;
        const bf16x8 a_ds = *(const bf16x8*)(nps + 32);
        const bf16x8 a_dr = *(const bf16x8*)(npr + 32);
        const f32x4 e0v = __builtin_nontemporal_load((const f32x4*)(ef + (size_t)e * DD + q * 8));
        const f32x4 e1v = __builtin_nontemporal_load((const f32x4*)(ef + (size_t)e * DD + q * 8) + 1);

        #pragma unroll
        for (int j = 0; j < 8; ++j)
            hd[c * DSTR + q * 8 + j] =
                bf2f((unsigned short)a_dr[j]) - bf2f((unsigned short)a_ds[j]);
        if (q == 0) rb[c] = ri;

        bf16x8 aef;
        aef[0] = (short)f2bf(e0v[0]); aef[1] = (short)f2bf(e0v[1]);
        aef[2] = (short)f2bf(e0v[2]); aef[3] = (short)f2bf(e0v[3]);
        aef[4] = (short)f2bf(e1v[0]); aef[5] = (short)f2bf(e1v[1]);
        aef[6] = (short)f2bf(e1v[2]); aef[7] = (short)f2bf(e1v[3]);

        const bf16x8 af[5] = {a_ss, a_sr, a_ds, a_dr, aef};
        f32x4 c0[4] = {f32x4{0,0,0,0}, f32x4{0,0,0,0}, f32x4{0,0,0,0}, f32x4{0,0,0,0}};
        #pragma unroll
        for (int kk = 0; kk < 5; ++kk) {
            #pragma unroll
            for (int t = 0; t < 4; ++t) {
                const bf16x8 b = *(const bf16x8*)(wlds + (kk * 4 + t) * 512 + lane * 8);
                c0[t] = __builtin_amdgcn_mfma_f32_16x16x32_bf16(af[kk], b, c0[t], 0, 0, 0);
            }
        }
        #pragma unroll
        for (int t = 0; t < 4; ++t) {
            #pragma unroll
            for (int r = 0; r < 4; ++r) {
                const float v = fmaxf(c0[t][r] + b0t[t], 0.0f);
                xb[(q * 4 + r) * XSTR + t * 16 + c] = f2bf(v);
            }
        }
        f32x4 c1[4] = {f32x4{0,0,0,0}, f32x4{0,0,0,0}, f32x4{0,0,0,0}, f32x4{0,0,0,0}};
        #pragma unroll
        for (int kk = 0; kk < 2; ++kk) {
            const bf16x8 a = *(const bf16x8*)(xb + c * XSTR + kk * 32 + q * 8);
            #pragma unroll
            for (int t = 0; t < 4; ++t)
                c1[t] = __builtin_amdgcn_mfma_f32_16x16x32_bf16(a, wf1[kk * 4 + t], c1[t], 0, 0, 0);
        }
        #pragma unroll
        for (int t = 0; t < 4; ++t) {
            #pragma unroll
            for (int r = 0; r < 4; ++r) {
                const float v = fmaxf(c1[t][r] + b1t[t], 0.0f);
                xb[(q * 4 + r) * XSTR + t * 16 + c] = f2bf(v);
            }
        }
        f32x4 c2[2] = {f32x4{0,0,0,0}, f32x4{0,0,0,0}};
        #pragma unroll
        for (int kk = 0; kk < 2; ++kk) {
            const bf16x8 a = *(const bf16x8*)(xb + c * XSTR + kk * 32 + q * 8);
            #pragma unroll
            for (int t = 0; t < 2; ++t)
                c2[t] = __builtin_amdgcn_mfma_f32_16x16x32_bf16(a, wf2[kk * 2 + t], c2[t], 0, 0, 0);
        }
        int rir[4];
        #pragma unroll
        for (int r = 0; r < 4; ++r) rir[r] = rb[q * 4 + r];
        #pragma unroll
        for (int t = 0; t < 2; ++t) {
            const int h = t * 16 + c;
            #pragma unroll
            for (int r = 0; r < 4; ++r) {
                const int ee = base + q * 4 + r;
                if (ee < E) {
                    const float psi = fmaxf(c2[t][r] + b2t[t], 0.0f);
                    const float d = hd[(q * 4 + r) * DSTR + h];
                    atomicAdd(agg + (size_t)rir[r] * DD + h, psi * d);
                }
            }
        }
    }
}

__global__ __launch_bounds__(256) void out_kernel(
    const float* __restrict__ h_d, const float* __restrict__ agg,
    const float* __restrict__ W, float* __restrict__ out, int N)
{
    const int idx = blockIdx.x * 256 + threadIdx.x;
    if (idx >= N * DD) return;
    const int n = idx >> 5;
    const int d = idx & 31;
    const float* arow = agg + (size_t)n * DD;
    float s = h_d[idx];
    #pragma unroll
    for (int k = 0; k < DD; ++k) s = fmaf(arow[k], W[k * DD + d], s);
    out[idx] = s;
}

extern "C" void kernel_launch(void* const* d_in, const int* in_sizes, int n_in,
                              void* d_out, int out_size, void* d_ws, size_t ws_size,
                              hipStream_t stream) {
    const float* h_d = (const float*)d_in[0];
    const float* h_s = (const float*)d_in[1];
    const float* ef  = (const float*)d_in[2];
    const int*   snd = (const int*)d_in[3];
    const int*   rcv = (const int*)d_in[4];
    const float* w0  = (const float*)d_in[5];
    const float* b0  = (const float*)d_in[6];
    const float* w1  = (const float*)d_in[7];
    const float* b1  = (const float*)d_in[8];
    const float* w2  = (const float*)d_in[9];
    const float* b2  = (const float*)d_in[10];
    const float* W   = (const float*)d_in[11];
    float* out = (float*)d_out;

    const int N = in_sizes[0] / DD;
    const int E = in_sizes[3];
    const int ntiles = (E + 15) / 16;
    const int nb = (N + 1023) / 1024;           // scan blocks (<=128)

    char* ws = (char*)d_ws;
    size_t off = 0;
    auto walloc = [&](size_t bytes) {
        char* ptr = ws + off; off += (bytes + 255) & ~(size_t)255; return ptr;
    };
    unsigned short* frags = (unsigned short*)walloc(32 * 512 * sizeof(unsigned short));
    unsigned short* npack = (unsigned short*)walloc((size_t)N * 64 * sizeof(unsigned short));
    int* cnt              = (int*)walloc((size_t)N * sizeof(int));
    int* btot             = (int*)walloc(128 * sizeof(int));
    int* boffs            = (int*)walloc(128 * sizeof(int));
    int* perm             = (int*)walloc((size_t)E * sizeof(int));
    // big tail allocs: sij (main) vs agg (fallback)
    const size_t need_main = off + (((size_t)E * DD * sizeof(unsigned short) + 255) & ~(size_t)255);

    if (need_main <= ws_size) {
        unsigned short* sij = (unsigned short*)walloc((size_t)E * DD * sizeof(unsigned short));
        (void)hipMemsetAsync(cnt, 0, (size_t)N * sizeof(int), stream);
        prep_weights<<<8, 256, 0, stream>>>(w0, w1, w2, frags);
        pack_hist<<<(N * 8 + 255) / 256, 256, 0, stream>>>(h_d, h_s, npack, rcv, cnt, N, E);
        scan1<<<nb, 1024, 0, stream>>>(cnt, btot, N);
        scan2<<<1, 128, 0, stream>>>(btot, boffs, nb);
        scatter_perm<<<(E + 255) / 256, 256, 0, stream>>>(rcv, cnt, boffs, perm, E);
        edge_psi<<<512, 512, 0, stream>>>(npack, ef, snd, rcv, frags,
                                          b0, b1, b2, sij, E, ntiles);
        aggregate_out<<<(N + 15) / 16, 256, 0, stream>>>(sij, perm, cnt, boffs,
                                                         h_d, W, out, N);
    } else {
        float* agg = (float*)walloc((size_t)N * DD * sizeof(float));
        (void)hipMemsetAsync(agg, 0, (size_t)N * DD * sizeof(float), stream);
        prep_weights<<<8, 256, 0, stream>>>(w0, w1, w2, frags);
        pack_hist<<<(N * 8 + 255) / 256, 256, 0, stream>>>(h_d, h_s, npack, rcv, nullptr, N, E);
        edge_atomic<<<512, 512, 0, stream>>>(npack, ef, snd, rcv, frags,
                                             b0, b1, b2, agg, E, ntiles);
        out_kernel<<<((N * DD) + 255) / 256, 256, 0, stream>>>(h_d, agg, W, out, N);
    }
}